// Round 10
// baseline (177.936 us; speedup 1.0000x reference)
//
#include <hip/hip_runtime.h>
#include <math.h>

// Problem constants (from reference): T=128, B=2048, D=256, ALPHA=0.5, VTH=1.0
#define TT 128
#define BB 2048
#define DDIM 256
#define BD (BB * DDIM)
#define TPB 64  // one wave per block; 32 KiB LDS -> 5 blocks/CU

// GL coefficients c[j] = prod_{i=1..j} (1 - (1+alpha)/i), computed in f64 then
// cast to f32 — exactly mirrors _gl_coeffs (float64 cumprod -> float32 cast).
struct Coeffs {
    float c[TT + 1];
};
static constexpr Coeffs make_coeffs() {
    Coeffs r{};
    r.c[0] = 1.0f;
    double cur = 1.0;
    for (int j = 1; j <= TT; ++j) {
        cur *= (1.0 - 1.5 / (double)j);  // (1+alpha) = 1.5
        r.c[j] = (float)cur;
    }
    return r;
}
static constexpr Coeffs CO = make_coeffs();

// One thread per (b,d) sequence — 16x16-tiled triangular convolution with the
// y-history homed in LDS (slot-major [slot][tid]).
//
// R1-R9 verdict: wherever the register allocator homes y[128], it costs ~1
// extra VALU op per FMA (AGPR per-use shuttle, R1/R9: 19K instrs/wave) or
// +600MB HBM (scratch, R7/R8). Only R7's tiled schedule hit the 1.2-op/FMA
// floor (11.7K instrs/wave). LDS is the home the allocator can't override:
//  - ds_read issues on the LDS pipe, overlapping FMA on the VALU pipe;
//    16 reads per 256-FMA tile is noise (LDS ~69 TB/s aggregate).
//  - slot-major layout: bank = tid%32, 2-way aliasing = free; every offset
//    (slot*256B <= 32.5KB) fits the ds immediate off one base -> no addr VALU.
//  - the asm memory clobber per step-block stops store->load forwarding from
//    re-materializing y in registers (the R9 failure).
// Working set without y[]: acc[16]+yt[16]+xv[16]+xnv[16]+coeff band ~ 100
// VGPRs -> fits arch VGPRs, nothing to spill.
// Bit-exactness: identical fmaf chain order to R1/R7/R9 (tiles ascend, s
// ascends within tile, diagonal last) — validated by three passing rounds.
__global__ __launch_bounds__(TPB) void gl_if_kernel(const float* __restrict__ x,
                                                    float* __restrict__ sp) {
    __shared__ float ylds[TT * TPB];  // 32 KiB, slot-major: ylds[s*TPB + tid]
    const int tid = threadIdx.x;
    const int g = blockIdx.x * TPB + tid;  // (b,d) flat index

    // x for step-block 0 (issued immediately; consumed after the prefetch of
    // block 1 is also in flight)
    float xv[16];
#pragma unroll
    for (int r = 0; r < 16; ++r) {
        xv[r] = x[g + (size_t)r * BD];
    }

#pragma unroll
    for (int K = 0; K < TT / 16; ++K) {
        // prefetch next block's x during this block's FMA wall
        float xnv[16];
        if (K < TT / 16 - 1) {
#pragma unroll
            for (int r = 0; r < 16; ++r) {
                xnv[r] = x[g + (size_t)(16 * (K + 1) + r) * BD];
            }
        }

        float acc[16];
#pragma unroll
        for (int r = 0; r < 16; ++r) acc[r] = 0.0f;

        // Full history tiles I < K: 16 LDS reads amortized over 256 FMAs.
#pragma unroll
        for (int I = 0; I < K; ++I) {
            float yt[16];
#pragma unroll
            for (int s = 0; s < 16; ++s) {
                yt[s] = ylds[(16 * I + s) * TPB + tid];
            }
#pragma unroll
            for (int r = 0; r < 16; ++r) {
#pragma unroll
                for (int s = 0; s < 16; ++s) {
                    // step k = 16K+r+1, slot i = 16I+s, coeff j = 16(K-I)+r-s
                    acc[r] = fmaf(CO.c[16 * (K - I) + r - s], yt[s], acc[r]);
                }
            }
        }

        // Diagonal tile + spike/reset (sequential part)
        float yn[16];
#pragma unroll
        for (int r = 0; r < 16; ++r) {
            float a = acc[r];
#pragma unroll
            for (int s = 0; s < r; ++s) {
                a = fmaf(CO.c[r - s], yn[s], a);
            }
            const float men0 = xv[r] - a;
            const float spike = (men0 > 1.0f) ? 1.0f : 0.0f;
            yn[r] = men0 - spike;  // VTH = 1.0
            sp[g + (size_t)(16 * K + r) * BD] = spike;
        }

        // Commit the new tile to the LDS history.
#pragma unroll
        for (int r = 0; r < 16; ++r) {
            ylds[(16 * K + r) * TPB + tid] = yn[r];
        }
        // Full memory clobber: forbids store->load forwarding of ylds into
        // the next K-blocks (which would resurrect the register-home problem).
        // The xnv loads above are issued BEFORE this point and consumed after,
        // giving them a full tile-phase of latency cover.
        asm volatile("" ::: "memory");

        if (K < TT / 16 - 1) {
#pragma unroll
            for (int r = 0; r < 16; ++r) xv[r] = xnv[r];
        }
    }
}

// Lorentz expmap: per row b, vv = -v0^2 + sum_{d>=1} vd^2; s = sqrt(max(vv,eps));
// out = cosh(s)*z + (sinh(s)/s)*v.  One block per row, one thread per d.
__global__ __launch_bounds__(256) void expmap_kernel(const float* __restrict__ v,
                                                     const float* __restrict__ z,
                                                     float* __restrict__ out) {
    const int b = blockIdx.x;
    const int d = threadIdx.x;
    const size_t idx = (size_t)b * DDIM + d;
    const float vd = v[idx];

    float term = vd * vd;
    if (d == 0) term = -term;

    // reduce across the 256-thread block (4 waves of 64)
    float sum = term;
#pragma unroll
    for (int off = 32; off > 0; off >>= 1) sum += __shfl_down(sum, off, 64);

    __shared__ float ws[4];
    if ((threadIdx.x & 63) == 0) ws[threadIdx.x >> 6] = sum;
    __syncthreads();
    const float vv = ws[0] + ws[1] + ws[2] + ws[3];

    const float s2 = fmaxf(vv, 1e-6f);
    const float s = sqrtf(s2);
    const float ch = coshf(s);
    const float shs = sinhf(s) / s;

    out[idx] = ch * z[idx] + shs * vd;
}

extern "C" void kernel_launch(void* const* d_in, const int* in_sizes, int n_in,
                              void* d_out, int out_size, void* d_ws, size_t ws_size,
                              hipStream_t stream) {
    const float* x_seq = (const float*)d_in[0];
    const float* v_seq = (const float*)d_in[1];
    const float* z_seq = (const float*)d_in[2];

    float* s_out = (float*)d_out;                       // [T,B,D] spikes
    float* z_out = (float*)d_out + (size_t)TT * BD;     // [B,D] expmap

    gl_if_kernel<<<BD / TPB, TPB, 0, stream>>>(x_seq, s_out);
    expmap_kernel<<<BB, DDIM, 0, stream>>>(v_seq, z_seq, z_out);
}